// Round 2
// baseline (888.079 us; speedup 1.0000x reference)
//
#include <hip/hip_runtime.h>
#include <math.h>

typedef __attribute__((ext_vector_type(8))) short bf16x8;
typedef __attribute__((ext_vector_type(4))) float f32x4;

#define BSZ 8
#define SEQ 2048
#define DIM 512
#define BS_TOT (BSZ*SEQ)

__device__ __forceinline__ unsigned short f2bf(float f) {
    unsigned int u = __float_as_uint(f);
    unsigned int r = (u + 0x7fffu + ((u >> 16) & 1u)) >> 16;
    return (unsigned short)r;
}

__device__ __forceinline__ f32x4 mfma16(bf16x8 a, bf16x8 b, f32x4 c) {
    return __builtin_amdgcn_mfma_f32_16x16x32_bf16(a, b, c, 0, 0, 0);
}

// ---------------- fp32 -> bf16 conversion (vector4) ----------------
__global__ __launch_bounds__(256) void conv_f2b(const float* __restrict__ src,
                                                unsigned short* __restrict__ dst, int n4) {
    int i = blockIdx.x * blockDim.x + threadIdx.x;
    if (i < n4) {
        float4 v = ((const float4*)src)[i];
        ushort4 o;
        o.x = f2bf(v.x); o.y = f2bf(v.y); o.z = f2bf(v.z); o.w = f2bf(v.w);
        ((ushort4*)dst)[i] = o;
    }
}

// ---------------- per-point attr table, packed 8 floats ----------------
// {sin(lat/2), cos(lat/2), sin(lon/2), cos(lon/2), cos(lat), time, maskf, 0}
__global__ __launch_bounds__(256) void trig_prep(const float* __restrict__ lat,
                                                 const float* __restrict__ lon,
                                                 const float* __restrict__ tm,
                                                 const int* __restrict__ mask,
                                                 float* __restrict__ trigp) {
    int i = blockIdx.x * blockDim.x + threadIdx.x;
    if (i < BS_TOT) {
        const float RAD = 0.017453292519943295f;
        float la = lat[i] * RAD, lo = lon[i] * RAD;
        float4 a = {sinf(la * 0.5f), cosf(la * 0.5f), sinf(lo * 0.5f), cosf(lo * 0.5f)};
        float4 b = {cosf(la), tm[i], mask[i] ? 1.0f : 0.0f, 0.0f};
        ((float4*)trigp)[(size_t)i * 2] = a;
        ((float4*)trigp)[(size_t)i * 2 + 1] = b;
    }
}

// ---------------- fused QKV projection GEMM (bf16 MFMA) ----------------
// out[s][e] = sum_d x[s][d] * W[e][d] + b[e]; Q,K row-major; V transposed [b][e][s].
// Block: 256 thr = 4 waves; m-tile 128 (wave owns 32 rows), n-tile 64.
__global__ __launch_bounds__(256, 3) void qkv_gemm(
    const unsigned short* __restrict__ xb,
    const unsigned short* __restrict__ Wqb, const unsigned short* __restrict__ Wkb,
    const unsigned short* __restrict__ Wvb,
    const float* __restrict__ bq, const float* __restrict__ bk, const float* __restrict__ bv,
    unsigned short* __restrict__ Qb, unsigned short* __restrict__ Kb,
    unsigned short* __restrict__ VTb) {
    __shared__ __align__(16) unsigned short Ts[9216];   // max(128*72, 64*136)

    const int tid = threadIdx.x;
    const int lane = tid & 63, w = tid >> 6;
    const int lq = lane & 15, quad = lane >> 4;
    const int m0 = blockIdx.x * 128, n0 = blockIdx.y * 64;

    f32x4 acc[3][2][4];
    #pragma unroll
    for (int o = 0; o < 3; ++o)
        #pragma unroll
        for (int mi = 0; mi < 2; ++mi)
            #pragma unroll
            for (int c = 0; c < 4; ++c) acc[o][mi][c] = (f32x4){0.f, 0.f, 0.f, 0.f};

    const unsigned short* abase = xb + (size_t)(m0 + w * 32 + lq) * DIM + quad * 8;
    const unsigned short* Ws[3] = {Wqb, Wkb, Wvb};

    #pragma unroll
    for (int ks = 0; ks < 16; ++ks) {
        bf16x8 a0 = *(const bf16x8*)(abase + ks * 32);
        bf16x8 a1 = *(const bf16x8*)(abase + 16 * DIM + ks * 32);
        #pragma unroll
        for (int o = 0; o < 3; ++o) {
            const unsigned short* bb = Ws[o] + (size_t)(n0 + lq) * DIM + ks * 32 + quad * 8;
            #pragma unroll
            for (int c = 0; c < 4; ++c) {
                bf16x8 bf = *(const bf16x8*)(bb + (size_t)c * 16 * DIM);
                acc[o][0][c] = mfma16(a0, bf, acc[o][0][c]);
                acc[o][1][c] = mfma16(a1, bf, acc[o][1][c]);
            }
        }
    }

    const float* biases[3] = {bq, bk, bv};
    #pragma unroll
    for (int o = 0; o < 3; ++o) {
        __syncthreads();
        if (o < 2) {
            // pack row-major [m 128][e 64] with stride 72 (16B-aligned rows)
            #pragma unroll
            for (int c = 0; c < 4; ++c) {
                float be = biases[o][n0 + c * 16 + lq];
                #pragma unroll
                for (int mi = 0; mi < 2; ++mi)
                    #pragma unroll
                    for (int r = 0; r < 4; ++r)
                        Ts[(w * 32 + mi * 16 + quad * 4 + r) * 72 + c * 16 + lq] =
                            f2bf(acc[o][mi][c][r] + be);
            }
            __syncthreads();
            unsigned short* G = (o == 0) ? Qb : Kb;
            int mrow = tid >> 1, half = tid & 1;
            const unsigned short* lp = &Ts[mrow * 72 + half * 32];
            unsigned short* gp = G + (size_t)(m0 + mrow) * DIM + n0 + half * 32;
            #pragma unroll
            for (int u = 0; u < 4; ++u)
                *(uint4*)(gp + u * 8) = *(const uint4*)(lp + u * 8);
        } else {
            // pack transposed [e 64][m 128] with stride 136
            #pragma unroll
            for (int c = 0; c < 4; ++c) {
                float be = biases[2][n0 + c * 16 + lq];
                #pragma unroll
                for (int mi = 0; mi < 2; ++mi)
                    #pragma unroll
                    for (int r = 0; r < 4; ++r)
                        Ts[(c * 16 + lq) * 136 + w * 32 + mi * 16 + quad * 4 + r] =
                            f2bf(acc[2][mi][c][r] + be);
            }
            __syncthreads();
            int e = tid >> 2, mq = tid & 3;
            const unsigned short* lp = &Ts[e * 136 + mq * 32];
            unsigned short* gp = VTb + ((size_t)(m0 >> 11) * DIM + n0 + e) * SEQ +
                                 (m0 & 2047) + mq * 32;
            #pragma unroll
            for (int u = 0; u < 4; ++u)
                *(uint4*)(gp + u * 8) = *(const uint4*)(lp + u * 8);
        }
    }
}

// ---------------- fused flash attention with spatio-temporal bias ----------------
// Block: 256 thr = 4 waves = 2 qgroups x 2 split-halves.
// Wave (qg,h): 16 queries; QK over d-half h; PV over key-half h.
// One barrier per j-tile (double-buffered partial-score exchange).
#define BIAS_ONE(SF, K0, K1)                                               \
    {                                                                      \
        _Pragma("unroll")                                                  \
        for (int r = 0; r < 4; ++r) {                                      \
            float sdlat = K0.x * q_cla[r] - K0.y * q_sla[r];               \
            float sdlon = K0.z * q_clo[r] - K0.w * q_slo[r];               \
            float av = sdlat * sdlat + q_ca[r] * K1.x * (sdlon * sdlon);   \
            av = fminf(fmaxf(av, 0.f), 1.f);                               \
            float dsv = 12742.0f * asinf(sqrtf(av));                       \
            float dtv = fabsf(K1.y - q_t[r]);                              \
            float vv = SF[r] - dsv - dtv;                                  \
            SF[r] = (K1.z != 0.0f) ? vv : -1e9f;                           \
        }                                                                  \
    }

#define STORE_P(SF0, SF1)                                                  \
    {                                                                      \
        _Pragma("unroll")                                                  \
        for (int r = 0; r < 4; ++r) {                                      \
            Pl[wave][quad * 4 + r][lq] = f2bf(SF0[r]);                     \
            Pl[wave][quad * 4 + r][16 + lq] = f2bf(SF1[r]);                \
        }                                                                  \
    }

__global__ __launch_bounds__(256, 2) void attn_kernel(
    const unsigned short* __restrict__ Qb,
    const unsigned short* __restrict__ Kb,
    const unsigned short* __restrict__ VTb,
    const float* __restrict__ trigp,
    float* __restrict__ Out) {
    __shared__ float Sx[2][2][2][16][66];            // [buf][qg][h][q][key] 33792 B
    __shared__ __align__(16) unsigned short Pl[4][16][40];  // per-wave P, 5120 B

    const int tid = threadIdx.x, lane = tid & 63, wave = tid >> 6;
    const int lq = lane & 15, quad = lane >> 4;
    const int qg = wave >> 1, h = wave & 1;
    const int b = blockIdx.x;
    const int qbase = blockIdx.y * 32 + qg * 16;
    const size_t rowQ = (size_t)(b * SEQ + qbase);

    // Q fragments for d-half h (held in registers, reused over all 32 j-tiles)
    bf16x8 qf[8];
    {
        const unsigned short* qptr = Qb + (rowQ + lq) * DIM + h * 256 + quad * 8;
        #pragma unroll
        for (int kc = 0; kc < 8; ++kc) qf[kc] = *(const bf16x8*)(qptr + kc * 32);
    }
    // query attrs for rows quad*4+r
    float q_sla[4], q_cla[4], q_slo[4], q_clo[4], q_ca[4], q_t[4];
    #pragma unroll
    for (int r = 0; r < 4; ++r) {
        const float4* tp = (const float4*)(trigp + (rowQ + quad * 4 + r) * 8);
        float4 t0 = tp[0], t1 = tp[1];
        q_sla[r] = t0.x; q_cla[r] = t0.y; q_slo[r] = t0.z; q_clo[r] = t0.w;
        q_ca[r] = t1.x; q_t[r] = t1.y;
    }

    f32x4 acc[32];
    #pragma unroll
    for (int n = 0; n < 32; ++n) acc[n] = (f32x4){0.f, 0.f, 0.f, 0.f};
    float m_r[4], l_r[4];
    #pragma unroll
    for (int r = 0; r < 4; ++r) { m_r[r] = -__builtin_inff(); l_r[r] = 0.f; }

    const float scale = 0.04419417382415922f;   // 1/sqrt(512)

    #pragma unroll 1
    for (int jt = 0; jt < 32; ++jt) {
        const int j0 = jt * 64;
        // key attrs for owned half (2 keys per lane), loaded early
        const float4* kpa = (const float4*)(trigp + (size_t)(b * SEQ + j0 + h * 32 + lq) * 8);
        const float4* kpb = (const float4*)(trigp + (size_t)(b * SEQ + j0 + h * 32 + 16 + lq) * 8);
        float4 ka0 = kpa[0], ka1 = kpa[1];
        float4 kb0 = kpb[0], kb1 = kpb[1];

        // ---- QK^T partial over d-half h ----
        f32x4 sf[4];
        #pragma unroll
        for (int jf = 0; jf < 4; ++jf) sf[jf] = (f32x4){0.f, 0.f, 0.f, 0.f};
        {
            const unsigned short* kptr =
                Kb + (size_t)(b * SEQ + j0 + lq) * DIM + h * 256 + quad * 8;
            #pragma unroll
            for (int jf = 0; jf < 4; ++jf) {
                #pragma unroll
                for (int kc = 0; kc < 8; ++kc) {
                    bf16x8 kfr = *(const bf16x8*)(kptr + (size_t)jf * 16 * DIM + kc * 32);
                    sf[jf] = mfma16(qf[kc], kfr, sf[jf]);
                }
            }
        }
        #pragma unroll
        for (int jf = 0; jf < 4; ++jf)
            #pragma unroll
            for (int r = 0; r < 4; ++r) sf[jf][r] *= scale;
        // bias + mask on owned key-half only
        if (h == 0) {
            BIAS_ONE(sf[0], ka0, ka1);
            BIAS_ONE(sf[1], kb0, kb1);
        } else {
            BIAS_ONE(sf[2], ka0, ka1);
            BIAS_ONE(sf[3], kb0, kb1);
        }
        // ---- exchange partials (double-buffered, one barrier) ----
        {
            float* dst = &Sx[jt & 1][qg][h][0][0];
            #pragma unroll
            for (int jf = 0; jf < 4; ++jf)
                #pragma unroll
                for (int r = 0; r < 4; ++r)
                    dst[(quad * 4 + r) * 66 + jf * 16 + lq] = sf[jf][r];
        }
        __syncthreads();
        {
            const float* src = &Sx[jt & 1][qg][h ^ 1][0][0];
            #pragma unroll
            for (int jf = 0; jf < 4; ++jf)
                #pragma unroll
                for (int r = 0; r < 4; ++r) {
                    float v = sf[jf][r] + src[(quad * 4 + r) * 66 + jf * 16 + lq];
                    sf[jf][r] = (v < -5e8f) ? -1e9f : v;   // exact -1e9 for masked
                }
        }
        // ---- online softmax (wave-internal) ----
        float mt[4];
        #pragma unroll
        for (int r = 0; r < 4; ++r)
            mt[r] = fmaxf(fmaxf(sf[0][r], sf[1][r]), fmaxf(sf[2][r], sf[3][r]));
        #pragma unroll
        for (int o = 1; o < 16; o <<= 1)
            #pragma unroll
            for (int r = 0; r < 4; ++r) mt[r] = fmaxf(mt[r], __shfl_xor(mt[r], o, 16));
        float mn[4], al[4];
        bool ch = false;
        #pragma unroll
        for (int r = 0; r < 4; ++r) {
            mn[r] = fmaxf(m_r[r], mt[r]);
            ch = ch || (mn[r] > m_r[r]);
        }
        #pragma unroll
        for (int jf = 0; jf < 4; ++jf)
            #pragma unroll
            for (int r = 0; r < 4; ++r) sf[jf][r] = __expf(sf[jf][r] - mn[r]);
        float sm[4];
        #pragma unroll
        for (int r = 0; r < 4; ++r) sm[r] = (sf[0][r] + sf[1][r]) + (sf[2][r] + sf[3][r]);
        #pragma unroll
        for (int o = 1; o < 16; o <<= 1)
            #pragma unroll
            for (int r = 0; r < 4; ++r) sm[r] += __shfl_xor(sm[r], o, 16);
        #pragma unroll
        for (int r = 0; r < 4; ++r) {
            al[r] = __expf(m_r[r] - mn[r]);
            l_r[r] = l_r[r] * al[r] + sm[r];
            m_r[r] = mn[r];
        }
        if (__ballot(ch)) {
            #pragma unroll
            for (int n = 0; n < 32; ++n)
                #pragma unroll
                for (int r = 0; r < 4; ++r) acc[n][r] *= al[r];
        }
        // ---- P (owned half) -> bf16 A-layout via intra-wave LDS ----
        if (h == 0) { STORE_P(sf[0], sf[1]); } else { STORE_P(sf[2], sf[3]); }
        bf16x8 pf = *(const bf16x8*)&Pl[wave][lq][quad * 8];
        // ---- PV over owned key-half ----
        {
            const unsigned short* vptr =
                VTb + ((size_t)b * DIM + lq) * SEQ + j0 + h * 32 + quad * 8;
            #pragma unroll
            for (int nt = 0; nt < 32; ++nt) {
                bf16x8 vf = *(const bf16x8*)(vptr + (size_t)nt * 16 * SEQ);
                acc[nt] = mfma16(pf, vf, acc[nt]);
            }
        }
        __syncthreads();   // protect Sx buffer reuse (2-tile distance)
    }

    // ---- merge the two key-half partials of each qgroup, normalize, store ----
    float invl[4];
    #pragma unroll
    for (int r = 0; r < 4; ++r) invl[r] = 1.0f / l_r[r];
    float* Obuf = &Sx[0][0][0][0][0];   // reuse: [qg][q 16][d 128] stride 132
    #pragma unroll
    for (int c = 0; c < 4; ++c) {
        __syncthreads();
        if (h == 1) {
            #pragma unroll
            for (int nn = 0; nn < 8; ++nn)
                #pragma unroll
                for (int r = 0; r < 4; ++r)
                    Obuf[(qg * 16 + quad * 4 + r) * 132 + nn * 16 + lq] = acc[c * 8 + nn][r];
        }
        __syncthreads();
        if (h == 0) {
            #pragma unroll
            for (int nn = 0; nn < 8; ++nn)
                #pragma unroll
                for (int r = 0; r < 4; ++r) {
                    float v = (acc[c * 8 + nn][r] +
                               Obuf[(qg * 16 + quad * 4 + r) * 132 + nn * 16 + lq]) * invl[r];
                    Out[(rowQ + quad * 4 + r) * DIM + c * 128 + nn * 16 + lq] = v;
                }
        }
    }
}

extern "C" void kernel_launch(void* const* d_in, const int* in_sizes, int n_in,
                              void* d_out, int out_size, void* d_ws, size_t ws_size,
                              hipStream_t stream) {
    (void)in_sizes; (void)n_in; (void)out_size; (void)ws_size;
    const float* x    = (const float*)d_in[0];
    const float* tseq = (const float*)d_in[1];
    const float* lat  = (const float*)d_in[2];
    const float* lon  = (const float*)d_in[3];
    const int*   mk   = (const int*)d_in[4];
    const float* Wq   = (const float*)d_in[5];
    const float* bq   = (const float*)d_in[6];
    const float* Wk   = (const float*)d_in[7];
    const float* bk   = (const float*)d_in[8];
    const float* Wv   = (const float*)d_in[9];
    const float* bv   = (const float*)d_in[10];
    float* out = (float*)d_out;

    unsigned short* xb  = (unsigned short*)d_ws;
    unsigned short* Qb  = xb + (size_t)BS_TOT * DIM;
    unsigned short* Kb  = Qb + (size_t)BS_TOT * DIM;
    unsigned short* VTb = Kb + (size_t)BS_TOT * DIM;
    unsigned short* Wqb = VTb + (size_t)BS_TOT * DIM;
    unsigned short* Wkb = Wqb + DIM * DIM;
    unsigned short* Wvb = Wkb + DIM * DIM;
    float* trigp = (float*)(Wvb + DIM * DIM);   // 16384 x 8 floats

    conv_f2b<<<(BS_TOT * DIM / 4 + 255) / 256, 256, 0, stream>>>(x, xb, BS_TOT * DIM / 4);
    conv_f2b<<<(DIM * DIM / 4 + 255) / 256, 256, 0, stream>>>(Wq, Wqb, DIM * DIM / 4);
    conv_f2b<<<(DIM * DIM / 4 + 255) / 256, 256, 0, stream>>>(Wk, Wkb, DIM * DIM / 4);
    conv_f2b<<<(DIM * DIM / 4 + 255) / 256, 256, 0, stream>>>(Wv, Wvb, DIM * DIM / 4);
    trig_prep<<<(BS_TOT + 255) / 256, 256, 0, stream>>>(lat, lon, tseq, mk, trigp);

    qkv_gemm<<<dim3(BS_TOT / 128, DIM / 64), 256, 0, stream>>>(
        xb, Wqb, Wkb, Wvb, bq, bk, bv, Qb, Kb, VTb);

    attn_kernel<<<dim3(BSZ, SEQ / 32), 256, 0, stream>>>(Qb, Kb, VTb, trigp, out);
}

// Round 3
// 635.665 us; speedup vs baseline: 1.3971x; 1.3971x over previous
//
#include <hip/hip_runtime.h>
#include <math.h>

typedef __attribute__((ext_vector_type(8))) short bf16x8;
typedef __attribute__((ext_vector_type(4))) float f32x4;

#define BSZ 8
#define SEQ 2048
#define DIM 512
#define BS_TOT (BSZ*SEQ)

__device__ __forceinline__ unsigned short f2bf(float f) {
    unsigned int u = __float_as_uint(f);
    unsigned int r = (u + 0x7fffu + ((u >> 16) & 1u)) >> 16;
    return (unsigned short)r;
}

__device__ __forceinline__ f32x4 mfma16(bf16x8 a, bf16x8 b, f32x4 c) {
    return __builtin_amdgcn_mfma_f32_16x16x32_bf16(a, b, c, 0, 0, 0);
}

// ---------------- fp32 -> bf16 conversion (vector4) ----------------
__global__ __launch_bounds__(256) void conv_f2b(const float* __restrict__ src,
                                                unsigned short* __restrict__ dst, int n4) {
    int i = blockIdx.x * blockDim.x + threadIdx.x;
    if (i < n4) {
        float4 v = ((const float4*)src)[i];
        ushort4 o;
        o.x = f2bf(v.x); o.y = f2bf(v.y); o.z = f2bf(v.z); o.w = f2bf(v.w);
        ((ushort4*)dst)[i] = o;
    }
}

// ---------------- per-point attr table, packed 8 floats ----------------
// {sin(lat/2), cos(lat/2), sin(lon/2), cos(lon/2), cos(lat), time, maskf, 0}
__global__ __launch_bounds__(256) void trig_prep(const float* __restrict__ lat,
                                                 const float* __restrict__ lon,
                                                 const float* __restrict__ tm,
                                                 const int* __restrict__ mask,
                                                 float* __restrict__ trigp) {
    int i = blockIdx.x * blockDim.x + threadIdx.x;
    if (i < BS_TOT) {
        const float RAD = 0.017453292519943295f;
        float la = lat[i] * RAD, lo = lon[i] * RAD;
        float4 a = {sinf(la * 0.5f), cosf(la * 0.5f), sinf(lo * 0.5f), cosf(lo * 0.5f)};
        float4 b = {cosf(la), tm[i], mask[i] ? 1.0f : 0.0f, 0.0f};
        ((float4*)trigp)[(size_t)i * 2] = a;
        ((float4*)trigp)[(size_t)i * 2 + 1] = b;
    }
}

// ---------------- fused QKV projection GEMM (bf16 MFMA) ----------------
__global__ __launch_bounds__(256, 3) void qkv_gemm(
    const unsigned short* __restrict__ xb,
    const unsigned short* __restrict__ Wqb, const unsigned short* __restrict__ Wkb,
    const unsigned short* __restrict__ Wvb,
    const float* __restrict__ bq, const float* __restrict__ bk, const float* __restrict__ bv,
    unsigned short* __restrict__ Qb, unsigned short* __restrict__ Kb,
    unsigned short* __restrict__ VTb) {
    __shared__ __align__(16) unsigned short Ts[9216];

    const int tid = threadIdx.x;
    const int lane = tid & 63, w = tid >> 6;
    const int lq = lane & 15, quad = lane >> 4;
    const int m0 = blockIdx.x * 128, n0 = blockIdx.y * 64;

    f32x4 acc[3][2][4];
    #pragma unroll
    for (int o = 0; o < 3; ++o)
        #pragma unroll
        for (int mi = 0; mi < 2; ++mi)
            #pragma unroll
            for (int c = 0; c < 4; ++c) acc[o][mi][c] = (f32x4){0.f, 0.f, 0.f, 0.f};

    const unsigned short* abase = xb + (size_t)(m0 + w * 32 + lq) * DIM + quad * 8;
    const unsigned short* Ws[3] = {Wqb, Wkb, Wvb};

    #pragma unroll
    for (int ks = 0; ks < 16; ++ks) {
        bf16x8 a0 = *(const bf16x8*)(abase + ks * 32);
        bf16x8 a1 = *(const bf16x8*)(abase + 16 * DIM + ks * 32);
        #pragma unroll
        for (int o = 0; o < 3; ++o) {
            const unsigned short* bb = Ws[o] + (size_t)(n0 + lq) * DIM + ks * 32 + quad * 8;
            #pragma unroll
            for (int c = 0; c < 4; ++c) {
                bf16x8 bf = *(const bf16x8*)(bb + (size_t)c * 16 * DIM);
                acc[o][0][c] = mfma16(a0, bf, acc[o][0][c]);
                acc[o][1][c] = mfma16(a1, bf, acc[o][1][c]);
            }
        }
    }

    const float* biases[3] = {bq, bk, bv};
    #pragma unroll
    for (int o = 0; o < 3; ++o) {
        __syncthreads();
        if (o < 2) {
            #pragma unroll
            for (int c = 0; c < 4; ++c) {
                float be = biases[o][n0 + c * 16 + lq];
                #pragma unroll
                for (int mi = 0; mi < 2; ++mi)
                    #pragma unroll
                    for (int r = 0; r < 4; ++r)
                        Ts[(w * 32 + mi * 16 + quad * 4 + r) * 72 + c * 16 + lq] =
                            f2bf(acc[o][mi][c][r] + be);
            }
            __syncthreads();
            unsigned short* G = (o == 0) ? Qb : Kb;
            int mrow = tid >> 1, half = tid & 1;
            const unsigned short* lp = &Ts[mrow * 72 + half * 32];
            unsigned short* gp = G + (size_t)(m0 + mrow) * DIM + n0 + half * 32;
            #pragma unroll
            for (int u = 0; u < 4; ++u)
                *(uint4*)(gp + u * 8) = *(const uint4*)(lp + u * 8);
        } else {
            #pragma unroll
            for (int c = 0; c < 4; ++c) {
                float be = biases[2][n0 + c * 16 + lq];
                #pragma unroll
                for (int mi = 0; mi < 2; ++mi)
                    #pragma unroll
                    for (int r = 0; r < 4; ++r)
                        Ts[(c * 16 + lq) * 136 + w * 32 + mi * 16 + quad * 4 + r] =
                            f2bf(acc[2][mi][c][r] + be);
            }
            __syncthreads();
            int e = tid >> 2, mq = tid & 3;
            const unsigned short* lp = &Ts[e * 136 + mq * 32];
            unsigned short* gp = VTb + ((size_t)(m0 >> 11) * DIM + n0 + e) * SEQ +
                                 (m0 & 2047) + mq * 32;
            #pragma unroll
            for (int u = 0; u < 4; ++u)
                *(uint4*)(gp + u * 8) = *(const uint4*)(lp + u * 8);
        }
    }
}

// ---------------- phase 1: scores + bias + online softmax -> P' ----------------
// Block 256 thr = 4 waves, q-split (wave owns 32 q). Keys: quarter kh (512), 8 chunks x 64.
// Writes P' = exp(s - m_chunk) bf16; Mc per (row, 64-chunk); final (m,l) per (row, quarter).
__global__ __launch_bounds__(256, 2) void score_kernel(
    const unsigned short* __restrict__ Qb, const unsigned short* __restrict__ Kb,
    const float* __restrict__ trigp, unsigned short* __restrict__ Pbuf,
    float* __restrict__ Mc, float* __restrict__ Lq, float* __restrict__ Mf) {
    const int tid = threadIdx.x, lane = tid & 63, wave = tid >> 6;
    const int lq = lane & 15, quad = lane >> 4;
    const int qb = blockIdx.x, kh = blockIdx.y, b = blockIdx.z;
    const int q0 = qb * 128 + wave * 32;
    const size_t rowQ = (size_t)b * SEQ + q0;
    const float scale = 0.04419417382415922f;   // 1/sqrt(512)

    // Q fragments: 2 m-subtiles x 16 ksteps, held in registers all kernel
    bf16x8 qf[2][16];
    #pragma unroll
    for (int ms = 0; ms < 2; ++ms) {
        const unsigned short* qp = Qb + (rowQ + ms * 16 + lq) * DIM + quad * 8;
        #pragma unroll
        for (int ks = 0; ks < 16; ++ks) qf[ms][ks] = *(const bf16x8*)(qp + ks * 32);
    }
    // query attrs for the 8 C-rows this lane owns
    float qa_sla[2][4], qa_cla[2][4], qa_slo[2][4], qa_clo[2][4], qa_ca[2][4], qa_t[2][4];
    #pragma unroll
    for (int ms = 0; ms < 2; ++ms)
        #pragma unroll
        for (int r = 0; r < 4; ++r) {
            const float4* tp = (const float4*)(trigp + (rowQ + ms * 16 + quad * 4 + r) * 8);
            float4 t0 = tp[0], t1 = tp[1];
            qa_sla[ms][r] = t0.x; qa_cla[ms][r] = t0.y;
            qa_slo[ms][r] = t0.z; qa_clo[ms][r] = t0.w;
            qa_ca[ms][r] = t1.x; qa_t[ms][r] = t1.y;
        }

    float m_r[2][4], l_r[2][4];
    #pragma unroll
    for (int ms = 0; ms < 2; ++ms)
        #pragma unroll
        for (int r = 0; r < 4; ++r) { m_r[ms][r] = -__builtin_inff(); l_r[ms][r] = 0.f; }

    #pragma unroll 1
    for (int c = 0; c < 8; ++c) {
        __syncthreads();   // keep 4 waves in lockstep for L1 K-reuse (no LDS data dep)
        const int j0 = kh * 512 + c * 64;

        f32x4 acc[2][4];
        #pragma unroll
        for (int ms = 0; ms < 2; ++ms)
            #pragma unroll
            for (int cg = 0; cg < 4; ++cg) acc[ms][cg] = (f32x4){0.f, 0.f, 0.f, 0.f};

        const unsigned short* kp = Kb + ((size_t)b * SEQ + j0 + lq) * DIM + quad * 8;
        #pragma unroll
        for (int cg = 0; cg < 4; ++cg) {
            #pragma unroll
            for (int ks = 0; ks < 16; ++ks) {
                bf16x8 kf = *(const bf16x8*)(kp + (size_t)cg * 16 * DIM + ks * 32);
                acc[0][cg] = mfma16(qf[0][ks], kf, acc[0][cg]);
                acc[1][cg] = mfma16(qf[1][ks], kf, acc[1][cg]);
            }
        }

        float mt[2][4];
        #pragma unroll
        for (int ms = 0; ms < 2; ++ms)
            #pragma unroll
            for (int r = 0; r < 4; ++r) mt[ms][r] = -__builtin_inff();

        #pragma unroll
        for (int cg = 0; cg < 4; ++cg) {
            const float4* kp4 =
                (const float4*)(trigp + ((size_t)b * SEQ + j0 + cg * 16 + lq) * 8);
            float4 k0 = kp4[0], k1 = kp4[1];
            #pragma unroll
            for (int ms = 0; ms < 2; ++ms)
                #pragma unroll
                for (int r = 0; r < 4; ++r) {
                    float sdlat = k0.x * qa_cla[ms][r] - k0.y * qa_sla[ms][r];
                    float sdlon = k0.z * qa_clo[ms][r] - k0.w * qa_slo[ms][r];
                    float aa = sdlat * sdlat + qa_ca[ms][r] * k1.x * (sdlon * sdlon);
                    aa = fminf(fmaxf(aa, 0.f), 1.f);
                    float sv = acc[ms][cg][r] * scale - 12742.0f * asinf(sqrtf(aa)) -
                               fabsf(k1.y - qa_t[ms][r]);
                    sv = (k1.z != 0.0f) ? sv : -1e9f;
                    acc[ms][cg][r] = sv;
                    mt[ms][r] = fmaxf(mt[ms][r], sv);
                }
        }
        #pragma unroll
        for (int o = 1; o < 16; o <<= 1)
            #pragma unroll
            for (int ms = 0; ms < 2; ++ms)
                #pragma unroll
                for (int r = 0; r < 4; ++r)
                    mt[ms][r] = fmaxf(mt[ms][r], __shfl_xor(mt[ms][r], o));

        float sm[2][4];
        #pragma unroll
        for (int ms = 0; ms < 2; ++ms)
            #pragma unroll
            for (int r = 0; r < 4; ++r) {
                float mn = fmaxf(m_r[ms][r], mt[ms][r]);
                float al = __expf(m_r[ms][r] - mn);
                m_r[ms][r] = mn;
                l_r[ms][r] *= al;
                sm[ms][r] = 0.f;
            }
        #pragma unroll
        for (int cg = 0; cg < 4; ++cg)
            #pragma unroll
            for (int ms = 0; ms < 2; ++ms)
                #pragma unroll
                for (int r = 0; r < 4; ++r) {
                    float p = __expf(acc[ms][cg][r] - m_r[ms][r]);
                    acc[ms][cg][r] = p;
                    sm[ms][r] += p;
                }
        #pragma unroll
        for (int o = 1; o < 16; o <<= 1)
            #pragma unroll
            for (int ms = 0; ms < 2; ++ms)
                #pragma unroll
                for (int r = 0; r < 4; ++r) sm[ms][r] += __shfl_xor(sm[ms][r], o);
        #pragma unroll
        for (int ms = 0; ms < 2; ++ms)
            #pragma unroll
            for (int r = 0; r < 4; ++r) l_r[ms][r] += sm[ms][r];

        // store P' (bf16) and chunk max
        #pragma unroll
        for (int ms = 0; ms < 2; ++ms)
            #pragma unroll
            for (int cg = 0; cg < 4; ++cg)
                #pragma unroll
                for (int r = 0; r < 4; ++r)
                    Pbuf[(rowQ + ms * 16 + quad * 4 + r) * SEQ + j0 + cg * 16 + lq] =
                        f2bf(acc[ms][cg][r]);
        if (lq == 0) {
            #pragma unroll
            for (int ms = 0; ms < 2; ++ms)
                #pragma unroll
                for (int r = 0; r < 4; ++r)
                    Mc[(rowQ + ms * 16 + quad * 4 + r) * 32 + kh * 8 + c] = m_r[ms][r];
        }
    }
    if (lq == 0) {
        #pragma unroll
        for (int ms = 0; ms < 2; ++ms)
            #pragma unroll
            for (int r = 0; r < 4; ++r) {
                size_t idx = rowQ + ms * 16 + quad * 4 + r;
                Lq[idx * 4 + kh] = l_r[ms][r];
                Mf[idx * 4 + kh] = m_r[ms][r];
            }
    }
}

// ---------------- phase 1.5: per-row merge -> per-chunk scales ----------------
__global__ __launch_bounds__(256) void scale_kernel(
    const float* __restrict__ Mc, const float* __restrict__ Lq,
    const float* __restrict__ Mf, float* __restrict__ Sbuf) {
    int g = blockIdx.x * 256 + threadIdx.x;
    if (g >= BS_TOT) return;
    float M = -__builtin_inff();
    #pragma unroll
    for (int q = 0; q < 4; ++q) M = fmaxf(M, Mf[g * 4 + q]);
    float L = 0.f;
    #pragma unroll
    for (int q = 0; q < 4; ++q) L += Lq[g * 4 + q] * __expf(Mf[g * 4 + q] - M);
    float invL = 1.0f / L;
    int b = g >> 11, i = g & 2047;
    #pragma unroll
    for (int c = 0; c < 32; ++c)
        Sbuf[((size_t)b * 32 + c) * SEQ + i] = __expf(Mc[(size_t)g * 32 + c] - M) * invL;
}

// ---------------- phase 2: O = sum_c s_c * (P'_c V_c) ----------------
// Block 256 thr = 4 waves i-split; wave = 32 i x 64 d; K-loop 32 chunks of 64 keys.
__global__ __launch_bounds__(256) void pv_kernel(
    const unsigned short* __restrict__ Pbuf, const unsigned short* __restrict__ VTb,
    const float* __restrict__ Sbuf, float* __restrict__ Out) {
    const int tid = threadIdx.x, lane = tid & 63, wave = tid >> 6;
    const int lq = lane & 15, quad = lane >> 4;
    const int iblk = blockIdx.x, dblk = blockIdx.y, b = blockIdx.z;
    const int i0 = iblk * 128 + wave * 32, d0 = dblk * 64;

    const unsigned short* ap = Pbuf + ((size_t)b * SEQ + i0 + lq) * SEQ + quad * 8;
    const unsigned short* vp = VTb + ((size_t)b * DIM + d0 + lq) * SEQ + quad * 8;

    f32x4 am[2][4];
    #pragma unroll
    for (int ms = 0; ms < 2; ++ms)
        #pragma unroll
        for (int ns = 0; ns < 4; ++ns) am[ms][ns] = (f32x4){0.f, 0.f, 0.f, 0.f};

    #pragma unroll 1
    for (int cj = 0; cj < 32; ++cj) {
        __syncthreads();   // lockstep for L1 V-frag reuse (no LDS data dep)
        f32x4 pa[2][4];
        #pragma unroll
        for (int ms = 0; ms < 2; ++ms)
            #pragma unroll
            for (int ns = 0; ns < 4; ++ns) pa[ms][ns] = (f32x4){0.f, 0.f, 0.f, 0.f};

        #pragma unroll
        for (int ks = 0; ks < 2; ++ks) {
            bf16x8 af0 = *(const bf16x8*)(ap + cj * 64 + ks * 32);
            bf16x8 af1 = *(const bf16x8*)(ap + (size_t)16 * SEQ + cj * 64 + ks * 32);
            #pragma unroll
            for (int ns = 0; ns < 4; ++ns) {
                bf16x8 vf = *(const bf16x8*)(vp + (size_t)ns * 16 * SEQ + cj * 64 + ks * 32);
                pa[0][ns] = mfma16(af0, vf, pa[0][ns]);
                pa[1][ns] = mfma16(af1, vf, pa[1][ns]);
            }
        }
        #pragma unroll
        for (int ms = 0; ms < 2; ++ms)
            #pragma unroll
            for (int r = 0; r < 4; ++r) {
                float s = Sbuf[((size_t)b * 32 + cj) * SEQ + i0 + ms * 16 + quad * 4 + r];
                #pragma unroll
                for (int ns = 0; ns < 4; ++ns) am[ms][ns][r] += s * pa[ms][ns][r];
            }
    }

    #pragma unroll
    for (int ms = 0; ms < 2; ++ms)
        #pragma unroll
        for (int r = 0; r < 4; ++r) {
            size_t orow = ((size_t)b * SEQ + i0 + ms * 16 + quad * 4 + r) * DIM;
            #pragma unroll
            for (int ns = 0; ns < 4; ++ns)
                Out[orow + d0 + ns * 16 + lq] = am[ms][ns][r];
        }
}

extern "C" void kernel_launch(void* const* d_in, const int* in_sizes, int n_in,
                              void* d_out, int out_size, void* d_ws, size_t ws_size,
                              hipStream_t stream) {
    (void)in_sizes; (void)n_in; (void)out_size; (void)ws_size;
    const float* x    = (const float*)d_in[0];
    const float* tseq = (const float*)d_in[1];
    const float* lat  = (const float*)d_in[2];
    const float* lon  = (const float*)d_in[3];
    const int*   mk   = (const int*)d_in[4];
    const float* Wq   = (const float*)d_in[5];
    const float* bq   = (const float*)d_in[6];
    const float* Wk   = (const float*)d_in[7];
    const float* bk   = (const float*)d_in[8];
    const float* Wv   = (const float*)d_in[9];
    const float* bv   = (const float*)d_in[10];
    float* out = (float*)d_out;

    unsigned short* xb  = (unsigned short*)d_ws;
    unsigned short* Qb  = xb + (size_t)BS_TOT * DIM;
    unsigned short* Kb  = Qb + (size_t)BS_TOT * DIM;
    unsigned short* VTb = Kb + (size_t)BS_TOT * DIM;
    unsigned short* Wqb = VTb + (size_t)BS_TOT * DIM;
    unsigned short* Wkb = Wqb + DIM * DIM;
    unsigned short* Wvb = Wkb + DIM * DIM;
    float* trigp = (float*)(Wvb + DIM * DIM);                 // 16384 x 8 f32
    unsigned short* Pbuf = (unsigned short*)(trigp + (size_t)BS_TOT * 8);  // 33.6M bf16
    float* Mc = (float*)(Pbuf + (size_t)BS_TOT * SEQ);        // 16384 x 32
    float* Lq = Mc + (size_t)BS_TOT * 32;                     // 16384 x 4
    float* Mf = Lq + (size_t)BS_TOT * 4;                      // 16384 x 4
    float* Sbuf = Mf + (size_t)BS_TOT * 4;                    // 8 x 32 x 2048

    conv_f2b<<<(BS_TOT * DIM / 4 + 255) / 256, 256, 0, stream>>>(x, xb, BS_TOT * DIM / 4);
    conv_f2b<<<(DIM * DIM / 4 + 255) / 256, 256, 0, stream>>>(Wq, Wqb, DIM * DIM / 4);
    conv_f2b<<<(DIM * DIM / 4 + 255) / 256, 256, 0, stream>>>(Wk, Wkb, DIM * DIM / 4);
    conv_f2b<<<(DIM * DIM / 4 + 255) / 256, 256, 0, stream>>>(Wv, Wvb, DIM * DIM / 4);
    trig_prep<<<(BS_TOT + 255) / 256, 256, 0, stream>>>(lat, lon, tseq, mk, trigp);

    qkv_gemm<<<dim3(BS_TOT / 128, DIM / 64), 256, 0, stream>>>(
        xb, Wqb, Wkb, Wvb, bq, bk, bv, Qb, Kb, VTb);

    score_kernel<<<dim3(SEQ / 128, 4, BSZ), 256, 0, stream>>>(
        Qb, Kb, trigp, Pbuf, Mc, Lq, Mf);
    scale_kernel<<<(BS_TOT + 255) / 256, 256, 0, stream>>>(Mc, Lq, Mf, Sbuf);
    pv_kernel<<<dim3(SEQ / 128, DIM / 64, BSZ), 256, 0, stream>>>(
        Pbuf, VTb, Sbuf, out);
}